// Round 9
// baseline (9429.921 us; speedup 1.0000x reference)
//
#include <hip/hip_runtime.h>
#include <hip/hip_bf16.h>

#define B_ 1024
#define T_ 64
#define FEAT_ 1024
#define TENC_ 256
#define MAN_ 128
#define HID_ 2048
#define NG_ 8192   /* 4*HID */
#define IND_ 1408

typedef __attribute__((ext_vector_type(8))) short short8;
typedef __attribute__((ext_vector_type(4))) float f32x4;

typedef const __attribute__((address_space(1))) void as1_cvoid;
typedef __attribute__((address_space(3))) void as3_void;

static __device__ __forceinline__ float sigmoidf_(float x) {
  return 1.0f / (1.0f + __expf(-x));
}
static __device__ __forceinline__ float tanh_fast(float x) {
  return 1.0f - 2.0f / (__expf(2.0f * x) + 1.0f);
}
static __device__ __forceinline__ unsigned short f2b(float x) {
  __hip_bfloat16 h = __float2bfloat16(x);
  return *reinterpret_cast<unsigned short*>(&h);
}
static __device__ __forceinline__ float b2f(unsigned short u) {
  unsigned int v = ((unsigned int)u) << 16;
  return *reinterpret_cast<float*>(&v);
}

// float -> OCP fp8 e4m3fn (bias 7, max 448, no inf). round-half-up (bias ~negligible).
static __device__ __forceinline__ unsigned char f2fp8(float x) {
  unsigned int u = __float_as_uint(x);
  unsigned char s = (unsigned char)((u >> 31) << 7);
  float a = fabsf(x);
  if (a >= 448.f) return s | 0x7E;
  if (a < 0.015625f) {                    // < 2^-6: subnormal (ulp 2^-9)
    int q = (int)rintf(a * 512.f);        // q in [0,8]; 8 == 2^-6 == 0x08
    return s | (unsigned char)q;
  }
  unsigned int b = __float_as_uint(a) + 0x80000;  // round at mantissa bit 20
  int e = (int)(b >> 23) - 127;
  unsigned int m = (b >> 20) & 7;
  return s | (unsigned char)(((e + 7) << 3) | m);
}

// gate permutation: new col p -> original gate-matrix row
// gate = (p>>4)&3, h = (p>>7)*32 + ((p>>6)&1)*16 + (p&15)
static __device__ __forceinline__ int gate_perm(int p) {
  int h = ((p >> 7) << 5) + (((p >> 6) & 1) << 4) + (p & 15);
  int gate = (p >> 4) & 3;
  return gate * HID_ + h;
}

__device__ __forceinline__ void gload16(const void* g, void* l) {
  __builtin_amdgcn_global_load_lds((as1_cvoid*)g, (as3_void*)l, 16, 0, 0);
}

// ---------------- small prep kernels ----------------

__global__ void zero_u32(unsigned int* p, long n) {
  long i = (long)blockIdx.x * blockDim.x + threadIdx.x;
  if (i < n) p[i] = 0u;
}

// X [b][t][f] fp32 -> Xtm [t][b][f] bf16
__global__ void pack_x_tm(const float* __restrict__ src, unsigned short* __restrict__ dst) {
  int c = threadIdx.x * 4;
  int bt = blockIdx.x;
  int b = bt >> 6, t = bt & 63;
  float4 v = *reinterpret_cast<const float4*>(&src[((long)b * T_ + t) * FEAT_ + c]);
  ushort4 o;
  o.x = f2b(v.x); o.y = f2b(v.y); o.z = f2b(v.z); o.w = f2b(v.w);
  *reinterpret_cast<ushort4*>(&dst[((long)t * B_ + b) * FEAT_ + c]) = o;
}

// fp32 (rows x cols slice) -> contiguous bf16
__global__ void pack_bf16(const float* __restrict__ src, long ld, long off,
                          unsigned short* __restrict__ dst, long cols) {
  long c = ((long)blockIdx.x * blockDim.x + threadIdx.x) * 4;
  if (c >= cols) return;
  long r = blockIdx.y;
  float4 v = *reinterpret_cast<const float4*>(&src[r * ld + off + c]);
  ushort4 o;
  o.x = f2b(v.x); o.y = f2b(v.y); o.z = f2b(v.z); o.w = f2b(v.w);
  *reinterpret_cast<ushort4*>(&dst[r * cols + c]) = o;
}

// one-pass W_ih split: row rd (gate-permuted from src), cols -> Wx | Wy | Wte (bf16)
__global__ void pack_wih(const float* __restrict__ W_ih,
                         unsigned short* __restrict__ Wx,
                         unsigned short* __restrict__ Wy,
                         unsigned short* __restrict__ Wte) {
  int c = (blockIdx.x * 256 + threadIdx.x) * 4;
  if (c >= IND_) return;
  long rd = blockIdx.y;
  long rs = gate_perm((int)rd);
  float4 v = *reinterpret_cast<const float4*>(&W_ih[rs * IND_ + c]);
  ushort4 o;
  o.x = f2b(v.x); o.y = f2b(v.y); o.z = f2b(v.z); o.w = f2b(v.w);
  if (c < FEAT_) {
    *reinterpret_cast<ushort4*>(&Wx[rd * FEAT_ + c]) = o;
  } else if (c < FEAT_ + MAN_) {
    *reinterpret_cast<ushort4*>(&Wy[rd * MAN_ + (c - FEAT_)]) = o;
  } else {
    *reinterpret_cast<ushort4*>(&Wte[rd * TENC_ + (c - FEAT_ - MAN_)]) = o;
  }
}

// WmuT[n][m] = bf16(W_mu[m][n]);  W_mu: (MAN_, HID_)
__global__ void transpose_to_bf16(const float* __restrict__ src, unsigned short* __restrict__ dst) {
  int i = blockIdx.x * 256 + threadIdx.x;       // over HID_*MAN_
  int n = i >> 7, m = i & 127;
  dst[i] = f2b(src[(long)m * HID_ + n]);
}

// permuted: bvec2[p] = (b_ih + b_hh + b_mu@Wy^T)[gate_perm(p)];  nbm[p] = -(b_mu@Wy^T)[gate_perm(p)]
__global__ void bias_prep(const float* __restrict__ W_ih, const float* __restrict__ b_ih,
                          const float* __restrict__ b_hh, const float* __restrict__ b_mu,
                          float* __restrict__ bvec2, float* __restrict__ nbm) {
  int p = blockIdx.x * 256 + threadIdx.x;
  if (p >= NG_) return;
  int g = gate_perm(p);
  const float* wy = &W_ih[(long)g * IND_ + FEAT_];
  float s = 0.f;
  #pragma unroll 8
  for (int m = 0; m < MAN_; ++m) s += b_mu[m] * wy[m];
  bvec2[p] = b_ih[g] + b_hh[g] + s;
  nbm[p] = -s;
}

__global__ void out_t0(const float* __restrict__ y0, float* __restrict__ out) {
  int i = blockIdx.x * 256 + threadIdx.x;       // over B_*MAN_
  int b = i >> 7, m = i & 127;
  out[(long)b * (T_ * MAN_) + m] = y0[i];
}

// quantize Whhf (bf16, gate-perm rows) -> fp8 with per-row pow2 scale; invs[row] undoes
// (row scale) x (h scale 256) in the step epilogue. One block per row.
__global__ void quant_w8(const unsigned short* __restrict__ Wbf,
                         unsigned char* __restrict__ W8,
                         float* __restrict__ invs) {
  const int row = blockIdx.x;
  const unsigned short* wr = Wbf + (long)row * HID_;
  const int i0 = threadIdx.x * 8;               // 256 thr x 8 = 2048 = HID_
  short8 v = *reinterpret_cast<const short8*>(&wr[i0]);
  float mx = 0.f;
  #pragma unroll
  for (int j = 0; j < 8; ++j) mx = fmaxf(mx, fabsf(b2f((unsigned short)v[j])));
  #pragma unroll
  for (int o = 32; o > 0; o >>= 1) mx = fmaxf(mx, __shfl_down(mx, o));
  __shared__ float red[4];
  if ((threadIdx.x & 63) == 0) red[threadIdx.x >> 6] = mx;
  __syncthreads();
  float m4 = fmaxf(fmaxf(red[0], red[1]), fmaxf(red[2], red[3]));
  float scale, inv;
  if (m4 < 1e-30f) { scale = 0.f; inv = 0.f; }
  else {
    int e = ilogbf(m4);
    scale = ldexpf(1.f, 7 - e);                 // row max -> [128,256)
    inv = ldexpf(1.f, e - 15);                  // 2^(e-7) / 256
  }
  if (threadIdx.x == 0) invs[row] = inv;
  unsigned long long packed = 0;
  #pragma unroll
  for (int j = 0; j < 8; ++j)
    packed |= (unsigned long long)f2fp8(b2f((unsigned short)v[j]) * scale) << (8 * j);
  *reinterpret_cast<unsigned long long*>(&W8[(long)row * HID_ + i0]) = packed;
}

// ---------------- generic bf16 MFMA GEMM: C = A @ W^T (+bias[col]) (+addmat) ----------
// (prep / prologue / final GEMMs; R2-proven single-buffer 2-barrier structure)
// SMODE: 0 fp32 store; 1 bf16 store; 2 decoder scatter; 3 fused cell (q addmat/addmat2);
//        4 bf16 q-layout store. AMODE: 0 none; 3 fp32 addmat[gate_perm(row)*N+col];
//        5 bf16 q-layout addmat.
template<int SMODE, int AMODE>
__global__ __launch_bounds__(256, 2)
void gemm_bt(const unsigned short* __restrict__ A1, long lda1,
             const unsigned short* __restrict__ A2, long lda2, int K1,
             const unsigned short* __restrict__ W1, const unsigned short* __restrict__ W2,
             int N, int K,
             const float* __restrict__ bias,
             const void* __restrict__ addmat, const void* __restrict__ addmat2,
             void* __restrict__ outp, long ldo,
             float* __restrict__ cstate, unsigned short* __restrict__ hout)
{
  __shared__ unsigned short As[128 * 64];
  __shared__ unsigned short Bs[128 * 64];
  const int tid = threadIdx.x, lane = tid & 63, wave = tid >> 6;
  const long bm = blockIdx.x, bn = blockIdx.y;

  f32x4 acc[4][4] = {};

  const int nkt = K >> 6;
  const int wm = wave >> 1, wn = wave & 1;
  const int lr = lane & 15, lq = lane >> 4;

  for (int kt = 0; kt < nkt; ++kt) {
    const int k0 = kt << 6;
    const unsigned short* Ab; long lda; const unsigned short* Wb; long ldw; int ko;
    if (k0 < K1) { Ab = A1; lda = lda1; Wb = W1; ldw = K1;      ko = k0; }
    else         { Ab = A2; lda = lda2; Wb = W2; ldw = K - K1;  ko = k0 - K1; }
    __syncthreads();
    #pragma unroll
    for (int it = 0; it < 4; ++it) {
      const int c0 = it * 256 + wave * 64;
      const int c = c0 + lane;
      const int row = c >> 3, sub = c & 7;
      gload16(Ab + (bm * 128 + row) * lda + ko + sub * 8, &As[c0 * 8]);
      gload16(Wb + (bn * 128 + row) * ldw + ko + sub * 8, &Bs[c0 * 8]);
    }
    __syncthreads();
    #pragma unroll
    for (int kk = 0; kk < 2; ++kk) {
      short8 av[4], bv[4];
      const int lk = kk * 32 + lq * 8;
      #pragma unroll
      for (int m = 0; m < 4; ++m)
        av[m] = *reinterpret_cast<const short8*>(&As[(wm * 64 + m * 16 + lr) * 64 + lk]);
      #pragma unroll
      for (int n = 0; n < 4; ++n)
        bv[n] = *reinterpret_cast<const short8*>(&Bs[(wn * 64 + n * 16 + lr) * 64 + lk]);
      #pragma unroll
      for (int m = 0; m < 4; ++m)
        #pragma unroll
        for (int n = 0; n < 4; ++n)
          acc[m][n] = __builtin_amdgcn_mfma_f32_16x16x32_bf16(av[m], bv[n], acc[m][n], 0, 0, 0);
    }
  }

  const long grp = bn * 128 + wn * 64;

  if constexpr (SMODE == 3) {
    const int hcol = (int)bn * 32 + wn * 16 + lr;
    #pragma unroll
    for (int m = 0; m < 4; ++m) {
      #pragma unroll
      for (int r2 = 0; r2 < 4; ++r2) {
        const long row = bm * 128 + wm * 64 + m * 16 + lq * 4 + r2;
        const long qbase = row * (long)N + grp + lr * 4;
        ushort4 tq = *reinterpret_cast<const ushort4*>(
            &((const unsigned short*)addmat2)[qbase]);
        float gi = acc[m][0][r2] + b2f(tq.x);
        float gf = acc[m][1][r2] + b2f(tq.y);
        float gg = acc[m][2][r2] + b2f(tq.z);
        float go = acc[m][3][r2] + b2f(tq.w);
        if (addmat) {
          ushort4 gq = *reinterpret_cast<const ushort4*>(
              &((const unsigned short*)addmat)[qbase]);
          gi += b2f(gq.x); gf += b2f(gq.y); gg += b2f(gq.z); go += b2f(gq.w);
        }
        const long ci = row * HID_ + hcol;
        float c = cstate[ci];
        c = sigmoidf_(gf) * c + sigmoidf_(gi) * tanh_fast(gg);
        cstate[ci] = c;
        hout[ci] = f2b(sigmoidf_(go) * tanh_fast(c));
      }
    }
    return;
  }

  if constexpr (SMODE == 4) {
    #pragma unroll
    for (int m = 0; m < 4; ++m) {
      #pragma unroll
      for (int r2 = 0; r2 < 4; ++r2) {
        const long row = bm * 128 + wm * 64 + m * 16 + lq * 4 + r2;
        float v[4];
        #pragma unroll
        for (int n = 0; n < 4; ++n) {
          const long col = grp + n * 16 + lr;
          v[n] = acc[m][n][r2] + (bias ? bias[col] : 0.0f);
        }
        if constexpr (AMODE == 5) {
          ushort4 a4 = *reinterpret_cast<const ushort4*>(
              &((const unsigned short*)addmat)[row * (long)N + grp + lr * 4]);
          v[0] += b2f(a4.x); v[1] += b2f(a4.y); v[2] += b2f(a4.z); v[3] += b2f(a4.w);
        }
        ushort4 o;
        o.x = f2b(v[0]); o.y = f2b(v[1]); o.z = f2b(v[2]); o.w = f2b(v[3]);
        *reinterpret_cast<ushort4*>(
            &reinterpret_cast<unsigned short*>(outp)[row * ldo + grp + lr * 4]) = o;
      }
    }
    return;
  }

  // standard epilogues
  #pragma unroll
  for (int m = 0; m < 4; ++m) {
    #pragma unroll
    for (int n = 0; n < 4; ++n) {
      const long col = grp + n * 16 + lr;
      const float bvv = bias ? bias[col] : 0.0f;
      #pragma unroll
      for (int r2 = 0; r2 < 4; ++r2) {
        const long row = bm * 128 + wm * 64 + m * 16 + lq * 4 + r2;
        float v = acc[m][n][r2] + bvv;
        if constexpr (AMODE == 3) v += ((const float*)addmat)[(long)gate_perm((int)row) * N + col];
        if constexpr (SMODE == 0) {
          reinterpret_cast<float*>(outp)[row * ldo + col] = v;
        } else if constexpr (SMODE == 1) {
          reinterpret_cast<unsigned short*>(outp)[row * ldo + col] = f2b(v);
        } else {
          const long bb = row & 1023, tt = (row >> 10) + 1;
          reinterpret_cast<float*>(outp)[bb * (T_ * MAN_) + tt * MAN_ + col] = v;
        }
      }
    }
  }
}

// ---------------- fused step kernel: fp8 h-GEMM+cell  ∥  bf16 xg GEMM for t+1 ----------
// Grid 1024 (512 step + 512 xg; last step 512). Step role: h8 (fp8, x256) @ Whh8^T
// (fp8, per-row pow2 scale) with BK=128 K-elements in the SAME 16KB LDS tiles ->
// half the K-tiles/barriers of bf16. Epilogue applies invs[col] then adds bf16
// xg + TB, runs the cell, writes h as bf16 (for Y-GEMM) AND fp8 x256 (next step).
__global__ __launch_bounds__(256, 2)
void step_fused(const unsigned char* __restrict__ Whh8,
                const float* __restrict__ invs,
                const unsigned short* __restrict__ Wx,
                const unsigned short* __restrict__ Xt1,    // Xtm slab t+1 (or null)
                const unsigned short* __restrict__ xg_rd,  // ring slab t   (q-layout)
                unsigned short* __restrict__ xg_wr,        // ring slab t+1 (or null)
                const unsigned short* __restrict__ TBq,    // q-layout TB for step t
                const unsigned char* __restrict__ h8_rd,   // fp8 h_{t-1} (x256)
                unsigned char* __restrict__ h8_wr,         // fp8 h_t     (x256)
                unsigned short* __restrict__ hout,         // bf16 h_t (for Y-GEMM)
                float* __restrict__ cstate)
{
  __shared__ unsigned char smem[32768];
  const int tid = threadIdx.x, lane = tid & 63, wave = tid >> 6;
  const int flat = (int)blockIdx.x;
  const bool isStep = flat < 512;
  const int f = isStep ? flat : flat - 512;
  const int j = f >> 3;
  const long bm = j >> 3;                       // 8 values
  const long bn = (long)(f & 7) * 8 + (j & 7);  // 64 values, XCD-contiguous
  const int wm = wave >> 1, wn = wave & 1;
  const int lr = lane & 15, lq = lane >> 4;
  const long grp = bn * 128 + wn * 64;

  f32x4 acc[4][4] = {};

  if (isStep) {
    unsigned char* As = smem;
    unsigned char* Bs = smem + 16384;
    for (int kt = 0; kt < HID_ / 128; ++kt) {     // 16 K-tiles of 128 fp8 elements
      const int ko = kt << 7;                      // byte == element offset
      __syncthreads();
      #pragma unroll
      for (int it = 0; it < 4; ++it) {
        const int c0 = it * 256 + wave * 64;
        const int c = c0 + lane;
        const int row = c >> 3, sub = c & 7;       // 8 lanes x 16B = 128B per row
        gload16(h8_rd + (bm * 128 + row) * HID_ + ko + sub * 16, As + c0 * 16);
        gload16(Whh8  + (bn * 128 + row) * HID_ + ko + sub * 16, Bs + c0 * 16);
      }
      __syncthreads();
      #pragma unroll
      for (int kk = 0; kk < 4; ++kk) {
        long av[4], bv[4];
        const int lk = kk * 32 + lq * 8;
        #pragma unroll
        for (int m = 0; m < 4; ++m)
          av[m] = *reinterpret_cast<const long*>(As + (wm * 64 + m * 16 + lr) * 128 + lk);
        #pragma unroll
        for (int n = 0; n < 4; ++n)
          bv[n] = *reinterpret_cast<const long*>(Bs + (wn * 64 + n * 16 + lr) * 128 + lk);
        #pragma unroll
        for (int m = 0; m < 4; ++m)
          #pragma unroll
          for (int n = 0; n < 4; ++n)
            acc[m][n] = __builtin_amdgcn_mfma_f32_16x16x32_fp8_fp8(av[m], bv[n], acc[m][n], 0, 0, 0);
      }
    }

    // fused LSTM cell: n=0..3 fragments are i,f,g,o (scaled) for h = bn*32+wn*16+lr
    const int hcol = (int)bn * 32 + wn * 16 + lr;
    const float4 invq = *reinterpret_cast<const float4*>(&invs[grp + lr * 4]);
    #pragma unroll
    for (int m = 0; m < 4; ++m) {
      #pragma unroll
      for (int r2 = 0; r2 < 4; ++r2) {
        const long row = bm * 128 + wm * 64 + m * 16 + lq * 4 + r2;
        const long qbase = row * (long)NG_ + grp + lr * 4;
        ushort4 gq = *reinterpret_cast<const ushort4*>(&xg_rd[qbase]);
        ushort4 tq = *reinterpret_cast<const ushort4*>(&TBq[qbase]);
        float gi = acc[m][0][r2] * invq.x + b2f(gq.x) + b2f(tq.x);
        float gf = acc[m][1][r2] * invq.y + b2f(gq.y) + b2f(tq.y);
        float gg = acc[m][2][r2] * invq.z + b2f(gq.z) + b2f(tq.z);
        float go = acc[m][3][r2] * invq.w + b2f(gq.w) + b2f(tq.w);
        const long ci = row * HID_ + hcol;
        float c = cstate[ci];
        c = sigmoidf_(gf) * c + sigmoidf_(gi) * tanh_fast(gg);
        cstate[ci] = c;
        float h = sigmoidf_(go) * tanh_fast(c);
        hout[ci] = f2b(h);
        h8_wr[ci] = f2fp8(h * 256.f);
      }
    }
  } else {
    // bf16 xg role: x_{t+1} @ Wx^T, BK=64, q-layout store into ring slab t+1
    unsigned short* As = (unsigned short*)smem;
    unsigned short* Bs = (unsigned short*)(smem + 16384);
    for (int kt = 0; kt < FEAT_ / 64; ++kt) {
      const int ko = kt << 6;
      __syncthreads();
      #pragma unroll
      for (int it = 0; it < 4; ++it) {
        const int c0 = it * 256 + wave * 64;
        const int c = c0 + lane;
        const int row = c >> 3, sub = c & 7;
        gload16(Xt1 + (bm * 128 + row) * FEAT_ + ko + sub * 8, &As[c0 * 8]);
        gload16(Wx  + (bn * 128 + row) * FEAT_ + ko + sub * 8, &Bs[c0 * 8]);
      }
      __syncthreads();
      #pragma unroll
      for (int kk = 0; kk < 2; ++kk) {
        short8 av[4], bv[4];
        const int lk = kk * 32 + lq * 8;
        #pragma unroll
        for (int m = 0; m < 4; ++m)
          av[m] = *reinterpret_cast<const short8*>(&As[(wm * 64 + m * 16 + lr) * 64 + lk]);
        #pragma unroll
        for (int n = 0; n < 4; ++n)
          bv[n] = *reinterpret_cast<const short8*>(&Bs[(wn * 64 + n * 16 + lr) * 64 + lk]);
        #pragma unroll
        for (int m = 0; m < 4; ++m)
          #pragma unroll
          for (int n = 0; n < 4; ++n)
            acc[m][n] = __builtin_amdgcn_mfma_f32_16x16x32_bf16(av[m], bv[n], acc[m][n], 0, 0, 0);
      }
    }
    #pragma unroll
    for (int m = 0; m < 4; ++m) {
      #pragma unroll
      for (int r2 = 0; r2 < 4; ++r2) {
        const long row = bm * 128 + wm * 64 + m * 16 + lq * 4 + r2;
        ushort4 o;
        o.x = f2b(acc[m][0][r2]); o.y = f2b(acc[m][1][r2]);
        o.z = f2b(acc[m][2][r2]); o.w = f2b(acc[m][3][r2]);
        *reinterpret_cast<ushort4*>(&xg_wr[row * (long)NG_ + grp + lr * 4]) = o;
      }
    }
  }
}

// ---------------- launcher ----------------
extern "C" void kernel_launch(void* const* d_in, const int* in_sizes, int n_in,
                              void* d_out, int out_size, void* d_ws, size_t ws_size,
                              hipStream_t stream) {
  const float* input_repr = (const float*)d_in[0];
  const float* time_enc   = (const float*)d_in[1];
  const float* y0         = (const float*)d_in[2];
  const float* W_ih       = (const float*)d_in[3];
  const float* b_ih       = (const float*)d_in[4];
  const float* W_hh       = (const float*)d_in[5];
  const float* b_hh       = (const float*)d_in[6];
  const float* W_mu       = (const float*)d_in[7];
  const float* b_mu       = (const float*)d_in[8];
  float* out = (float*)d_out;

  char* ws = (char*)d_ws;
  auto alloc = [&](size_t bytes) {
    char* p = ws; ws += (bytes + 255) & ~(size_t)255; return p;
  };
  unsigned short* Xtm    = (unsigned short*)alloc((size_t)T_ * B_ * FEAT_ * 2);   // 134 MB (time-major)
  unsigned short* hstore = (unsigned short*)alloc((size_t)T_ * B_ * HID_ * 2);    // 268 MB
  float*  cst   = (float*)alloc((size_t)B_ * HID_ * 4);                           // 8.4 MB
  unsigned short* TB2 = (unsigned short*)alloc((size_t)B_ * NG_ * 2);             // 16.8 MB (bf16, q-layout)
  unsigned short* TB1 = (unsigned short*)alloc((size_t)B_ * NG_ * 2);             // 16.8 MB (q-layout)
  unsigned short* Whhf  = (unsigned short*)alloc((size_t)NG_ * HID_ * 2);         // 33.5 MB (perm rows)
  unsigned short* Wxbf  = (unsigned short*)alloc((size_t)NG_ * FEAT_ * 2);        // 16.8 MB (perm rows)
  unsigned short* Wybf  = (unsigned short*)alloc((size_t)NG_ * MAN_ * 2);         // (perm rows)
  unsigned short* Wtebf = (unsigned short*)alloc((size_t)NG_ * TENC_ * 2);        // (perm rows)
  unsigned short* WmuT  = (unsigned short*)alloc((size_t)HID_ * MAN_ * 2);
  unsigned short* Wmubf = (unsigned short*)alloc((size_t)MAN_ * HID_ * 2);
  unsigned short* tebf  = (unsigned short*)alloc((size_t)B_ * TENC_ * 2);
  unsigned short* y0bf  = (unsigned short*)alloc((size_t)B_ * MAN_ * 2);
  float* bvec2 = (float*)alloc(NG_ * 4);
  float* nbm   = (float*)alloc(NG_ * 4);
  unsigned char* Whh8 = (unsigned char*)alloc((size_t)NG_ * HID_);                // 16.8 MB fp8
  float* invs = (float*)alloc(NG_ * 4);
  unsigned char* h8ring = (unsigned char*)alloc((size_t)2 * B_ * HID_);           // 4.2 MB fp8
  size_t base_bytes = (size_t)(ws - (char*)d_ws);
  // xg 2-slab ring (33.6 MB), q-layout
  size_t xg_bytes = (size_t)2 * B_ * NG_ * 2;
  bool use_xg = (base_bytes + xg_bytes + 4096) <= ws_size;
  unsigned short* xgring = use_xg ? (unsigned short*)alloc(xg_bytes) : nullptr;

  // --- conversions / preps (all parallel work) ---
  pack_x_tm<<<B_ * T_, 256, 0, stream>>>(input_repr, Xtm);
  pack_wih<<<dim3(2, NG_), 256, 0, stream>>>(W_ih, Wxbf, Wybf, Wtebf);
  pack_bf16<<<dim3(2, MAN_), 256, 0, stream>>>(W_mu, HID_, 0, Wmubf, HID_);
  pack_bf16<<<dim3(1, B_), 256, 0, stream>>>(time_enc, TENC_, 0, tebf, TENC_);
  pack_bf16<<<dim3(1, B_), 256, 0, stream>>>(y0, MAN_, 0, y0bf, MAN_);
  transpose_to_bf16<<<1024, 256, 0, stream>>>(W_mu, WmuT);
  bias_prep<<<NG_ / 256, 256, 0, stream>>>(W_ih, b_ih, b_hh, b_mu, bvec2, nbm);
  zero_u32<<<(B_ * HID_ / 2 + 255) / 256, 256, 0, stream>>>((unsigned int*)hstore, (long)B_ * HID_ / 2); // h0 = 0 (bf16)
  zero_u32<<<(B_ * HID_ / 4 + 255) / 256, 256, 0, stream>>>((unsigned int*)h8ring, (long)B_ * HID_ / 4); // h0 = 0 (fp8 slab 0)
  zero_u32<<<(B_ * HID_ + 255) / 256, 256, 0, stream>>>((unsigned int*)cst, (long)B_ * HID_);            // c0 = 0
  out_t0<<<B_ * MAN_ / 256, 256, 0, stream>>>(y0, out);

  // Whhf = perm(W_hh) + permWy @ W_mu   (bf16, rows permuted)   M=NG_, N=HID_, K=MAN_
  gemm_bt<1, 3><<<dim3(NG_ / 128, HID_ / 128), 256, 0, stream>>>(
      Wybf, MAN_, Wybf, MAN_, MAN_, WmuT, WmuT, HID_, MAN_,
      nullptr, W_hh, nullptr, Whhf, HID_, nullptr, nullptr);
  // Whh8 = fp8(Whhf x rowscale), invs = 1/(rowscale*256)
  quant_w8<<<NG_, 256, 0, stream>>>(Whhf, Whh8, invs);
  // TB2 = q(te @ permWte^T + bvec2)                M=B_, N=NG_, K=TENC_ (bf16 q-layout)
  gemm_bt<4, 0><<<dim3(B_ / 128, NG_ / 128), 256, 0, stream>>>(
      tebf, TENC_, tebf, TENC_, TENC_, Wtebf, Wtebf, NG_, TENC_,
      bvec2, nullptr, nullptr, TB2, NG_, nullptr, nullptr);
  // TB1 = q(y0 @ permWy^T + nbm) + TB2(q)          M=B_, N=NG_, K=MAN_ (bf16 q-layout)
  gemm_bt<4, 5><<<dim3(B_ / 128, NG_ / 128), 256, 0, stream>>>(
      y0bf, MAN_, y0bf, MAN_, MAN_, Wybf, Wybf, NG_, MAN_,
      nbm, TB2, nullptr, TB1, NG_, nullptr, nullptr);

  if (use_xg) {
    // prologue: xg slab for t=1 into ring[1]   (M=B_, K=1024, q-layout)
    gemm_bt<4, 0><<<dim3(B_ / 128, NG_ / 128), 256, 0, stream>>>(
        Xtm + (long)B_ * FEAT_, FEAT_, Xtm, FEAT_, 1024,
        Wxbf, Wxbf, NG_, 1024,
        nullptr, nullptr, nullptr, xgring + (size_t)B_ * NG_, NG_, nullptr, nullptr);

    // 63 fused steps: fp8 h-GEMM+cell (slab t) ∥ bf16 xg GEMM (slab t+1)
    for (int t = 1; t < T_; ++t) {
      const bool hasxg = (t + 1 < T_);
      step_fused<<<hasxg ? 1024 : 512, 256, 0, stream>>>(
          Whh8, invs, Wxbf,
          hasxg ? Xtm + (long)(t + 1) * B_ * FEAT_ : nullptr,
          xgring + (size_t)(t & 1) * B_ * NG_,
          hasxg ? xgring + (size_t)((t + 1) & 1) * B_ * NG_ : nullptr,
          (t == 1 ? TB1 : TB2),
          h8ring + (size_t)((t - 1) & 1) * B_ * HID_,
          h8ring + (size_t)(t & 1) * B_ * HID_,
          hstore + (long)t * B_ * HID_,
          cst);
    }
  } else {
    // fallback (bf16, R2-proven): per-step K=3072 two-region GEMM + fused cell
    for (int t = 1; t < T_; ++t) {
      const unsigned short* A1 = Xtm + (long)t * B_ * FEAT_;
      const unsigned short* A2 = hstore + (long)(t - 1) * B_ * HID_;
      gemm_bt<3, 0><<<dim3(B_ / 128, NG_ / 128), 256, 0, stream>>>(
          A1, FEAT_, A2, HID_, FEAT_,
          Wxbf, Whhf, NG_, FEAT_ + HID_,
          nullptr, nullptr, (t == 1 ? TB1 : TB2), nullptr, 0,
          cst, hstore + (long)t * B_ * HID_);
    }
  }

  // --- all outputs y_t = h_t @ W_mu^T + b_mu in one GEMM, scattered into (B,T,MAN) ---
  gemm_bt<2, 0><<<dim3((T_ - 1) * B_ / 128, MAN_ / 128), 256, 0, stream>>>(
      hstore + (long)B_ * HID_, HID_, hstore + (long)B_ * HID_, HID_, HID_,
      Wmubf, Wmubf, MAN_, HID_,
      b_mu, nullptr, nullptr, out, 0, nullptr, nullptr);
}

// Round 10
// 4480.073 us; speedup vs baseline: 2.1049x; 2.1049x over previous
//
#include <hip/hip_runtime.h>
#include <hip/hip_bf16.h>

#define B_ 1024
#define T_ 64
#define FEAT_ 1024
#define TENC_ 256
#define MAN_ 128
#define HID_ 2048
#define NG_ 8192   /* 4*HID */
#define IND_ 1408

typedef __attribute__((ext_vector_type(8))) short short8;
typedef __attribute__((ext_vector_type(4))) float f32x4;

typedef const __attribute__((address_space(1))) void as1_cvoid;
typedef __attribute__((address_space(3))) void as3_void;

static __device__ __forceinline__ float sigmoidf_(float x) {
  return 1.0f / (1.0f + __expf(-x));
}
static __device__ __forceinline__ float tanh_fast(float x) {
  return 1.0f - 2.0f / (__expf(2.0f * x) + 1.0f);
}
static __device__ __forceinline__ unsigned short f2b(float x) {
  __hip_bfloat16 h = __float2bfloat16(x);
  return *reinterpret_cast<unsigned short*>(&h);
}
static __device__ __forceinline__ float b2f(unsigned short u) {
  unsigned int v = ((unsigned int)u) << 16;
  return *reinterpret_cast<float*>(&v);
}

// gate permutation: new col p -> original gate-matrix row
// gate = (p>>4)&3, h = (p>>7)*32 + ((p>>6)&1)*16 + (p&15)
static __device__ __forceinline__ int gate_perm(int p) {
  int h = ((p >> 7) << 5) + (((p >> 6) & 1) << 4) + (p & 15);
  int gate = (p >> 4) & 3;
  return gate * HID_ + h;
}

__device__ __forceinline__ void gload16(const unsigned short* g, unsigned short* l) {
  __builtin_amdgcn_global_load_lds((as1_cvoid*)g, (as3_void*)l, 16, 0, 0);
}

// ---------------- small prep kernels ----------------

__global__ void zero_u32(unsigned int* p, long n) {
  long i = (long)blockIdx.x * blockDim.x + threadIdx.x;
  if (i < n) p[i] = 0u;
}

// X [b][t][f] fp32 -> Xtm [t][b][f] bf16
__global__ void pack_x_tm(const float* __restrict__ src, unsigned short* __restrict__ dst) {
  int c = threadIdx.x * 4;
  int bt = blockIdx.x;
  int b = bt >> 6, t = bt & 63;
  float4 v = *reinterpret_cast<const float4*>(&src[((long)b * T_ + t) * FEAT_ + c]);
  ushort4 o;
  o.x = f2b(v.x); o.y = f2b(v.y); o.z = f2b(v.z); o.w = f2b(v.w);
  *reinterpret_cast<ushort4*>(&dst[((long)t * B_ + b) * FEAT_ + c]) = o;
}

// fp32 (rows x cols slice) -> contiguous bf16
__global__ void pack_bf16(const float* __restrict__ src, long ld, long off,
                          unsigned short* __restrict__ dst, long cols) {
  long c = ((long)blockIdx.x * blockDim.x + threadIdx.x) * 4;
  if (c >= cols) return;
  long r = blockIdx.y;
  float4 v = *reinterpret_cast<const float4*>(&src[r * ld + off + c]);
  ushort4 o;
  o.x = f2b(v.x); o.y = f2b(v.y); o.z = f2b(v.z); o.w = f2b(v.w);
  *reinterpret_cast<ushort4*>(&dst[r * cols + c]) = o;
}

// one-pass W_ih split: row rd (gate-permuted from src), cols -> Wx | Wy | Wte (bf16)
__global__ void pack_wih(const float* __restrict__ W_ih,
                         unsigned short* __restrict__ Wx,
                         unsigned short* __restrict__ Wy,
                         unsigned short* __restrict__ Wte) {
  int c = (blockIdx.x * 256 + threadIdx.x) * 4;
  if (c >= IND_) return;
  long rd = blockIdx.y;
  long rs = gate_perm((int)rd);
  float4 v = *reinterpret_cast<const float4*>(&W_ih[rs * IND_ + c]);
  ushort4 o;
  o.x = f2b(v.x); o.y = f2b(v.y); o.z = f2b(v.z); o.w = f2b(v.w);
  if (c < FEAT_) {
    *reinterpret_cast<ushort4*>(&Wx[rd * FEAT_ + c]) = o;
  } else if (c < FEAT_ + MAN_) {
    *reinterpret_cast<ushort4*>(&Wy[rd * MAN_ + (c - FEAT_)]) = o;
  } else {
    *reinterpret_cast<ushort4*>(&Wte[rd * TENC_ + (c - FEAT_ - MAN_)]) = o;
  }
}

// WmuT[n][m] = bf16(W_mu[m][n]);  W_mu: (MAN_, HID_)
__global__ void transpose_to_bf16(const float* __restrict__ src, unsigned short* __restrict__ dst) {
  int i = blockIdx.x * 256 + threadIdx.x;       // over HID_*MAN_
  int n = i >> 7, m = i & 127;
  dst[i] = f2b(src[(long)m * HID_ + n]);
}

// permuted: bvec2[p] = (b_ih + b_hh + b_mu@Wy^T)[gate_perm(p)];  nbm[p] = -(b_mu@Wy^T)[gate_perm(p)]
__global__ void bias_prep(const float* __restrict__ W_ih, const float* __restrict__ b_ih,
                          const float* __restrict__ b_hh, const float* __restrict__ b_mu,
                          float* __restrict__ bvec2, float* __restrict__ nbm) {
  int p = blockIdx.x * 256 + threadIdx.x;
  if (p >= NG_) return;
  int g = gate_perm(p);
  const float* wy = &W_ih[(long)g * IND_ + FEAT_];
  float s = 0.f;
  #pragma unroll 8
  for (int m = 0; m < MAN_; ++m) s += b_mu[m] * wy[m];
  bvec2[p] = b_ih[g] + b_hh[g] + s;
  nbm[p] = -s;
}

__global__ void out_t0(const float* __restrict__ y0, float* __restrict__ out) {
  int i = blockIdx.x * 256 + threadIdx.x;       // over B_*MAN_
  int b = i >> 7, m = i & 127;
  out[(long)b * (T_ * MAN_) + m] = y0[i];
}

// ---------------- generic bf16 MFMA GEMM: C = A @ W^T (+bias[col]) (+addmat) ----------
// (prep / prologue / final GEMMs; R2-proven single-buffer 2-barrier structure)
// SMODE: 0 fp32 store; 1 bf16 store; 2 decoder scatter; 3 fused cell (q addmat/addmat2);
//        4 bf16 q-layout store. AMODE: 0 none; 3 fp32 addmat[gate_perm(row)*N+col];
//        5 bf16 q-layout addmat.
template<int SMODE, int AMODE>
__global__ __launch_bounds__(256, 2)
void gemm_bt(const unsigned short* __restrict__ A1, long lda1,
             const unsigned short* __restrict__ A2, long lda2, int K1,
             const unsigned short* __restrict__ W1, const unsigned short* __restrict__ W2,
             int N, int K,
             const float* __restrict__ bias,
             const void* __restrict__ addmat, const void* __restrict__ addmat2,
             void* __restrict__ outp, long ldo,
             float* __restrict__ cstate, unsigned short* __restrict__ hout)
{
  __shared__ unsigned short As[128 * 64];
  __shared__ unsigned short Bs[128 * 64];
  const int tid = threadIdx.x, lane = tid & 63, wave = tid >> 6;
  const long bm = blockIdx.x, bn = blockIdx.y;

  f32x4 acc[4][4] = {};

  const int nkt = K >> 6;
  const int wm = wave >> 1, wn = wave & 1;
  const int lr = lane & 15, lq = lane >> 4;

  for (int kt = 0; kt < nkt; ++kt) {
    const int k0 = kt << 6;
    const unsigned short* Ab; long lda; const unsigned short* Wb; long ldw; int ko;
    if (k0 < K1) { Ab = A1; lda = lda1; Wb = W1; ldw = K1;      ko = k0; }
    else         { Ab = A2; lda = lda2; Wb = W2; ldw = K - K1;  ko = k0 - K1; }
    __syncthreads();
    #pragma unroll
    for (int it = 0; it < 4; ++it) {
      const int c0 = it * 256 + wave * 64;
      const int c = c0 + lane;
      const int row = c >> 3, sub = c & 7;
      gload16(Ab + (bm * 128 + row) * lda + ko + sub * 8, &As[c0 * 8]);
      gload16(Wb + (bn * 128 + row) * ldw + ko + sub * 8, &Bs[c0 * 8]);
    }
    __syncthreads();
    #pragma unroll
    for (int kk = 0; kk < 2; ++kk) {
      short8 av[4], bv[4];
      const int lk = kk * 32 + lq * 8;
      #pragma unroll
      for (int m = 0; m < 4; ++m)
        av[m] = *reinterpret_cast<const short8*>(&As[(wm * 64 + m * 16 + lr) * 64 + lk]);
      #pragma unroll
      for (int n = 0; n < 4; ++n)
        bv[n] = *reinterpret_cast<const short8*>(&Bs[(wn * 64 + n * 16 + lr) * 64 + lk]);
      #pragma unroll
      for (int m = 0; m < 4; ++m)
        #pragma unroll
        for (int n = 0; n < 4; ++n)
          acc[m][n] = __builtin_amdgcn_mfma_f32_16x16x32_bf16(av[m], bv[n], acc[m][n], 0, 0, 0);
    }
  }

  const long grp = bn * 128 + wn * 64;

  if constexpr (SMODE == 3) {
    const int hcol = (int)bn * 32 + wn * 16 + lr;
    #pragma unroll
    for (int m = 0; m < 4; ++m) {
      #pragma unroll
      for (int r2 = 0; r2 < 4; ++r2) {
        const long row = bm * 128 + wm * 64 + m * 16 + lq * 4 + r2;
        const long qbase = row * (long)N + grp + lr * 4;
        ushort4 tq = *reinterpret_cast<const ushort4*>(
            &((const unsigned short*)addmat2)[qbase]);
        float gi = acc[m][0][r2] + b2f(tq.x);
        float gf = acc[m][1][r2] + b2f(tq.y);
        float gg = acc[m][2][r2] + b2f(tq.z);
        float go = acc[m][3][r2] + b2f(tq.w);
        if (addmat) {
          ushort4 gq = *reinterpret_cast<const ushort4*>(
              &((const unsigned short*)addmat)[qbase]);
          gi += b2f(gq.x); gf += b2f(gq.y); gg += b2f(gq.z); go += b2f(gq.w);
        }
        const long ci = row * HID_ + hcol;
        float c = cstate[ci];
        c = sigmoidf_(gf) * c + sigmoidf_(gi) * tanh_fast(gg);
        cstate[ci] = c;
        hout[ci] = f2b(sigmoidf_(go) * tanh_fast(c));
      }
    }
    return;
  }

  if constexpr (SMODE == 4) {
    #pragma unroll
    for (int m = 0; m < 4; ++m) {
      #pragma unroll
      for (int r2 = 0; r2 < 4; ++r2) {
        const long row = bm * 128 + wm * 64 + m * 16 + lq * 4 + r2;
        float v[4];
        #pragma unroll
        for (int n = 0; n < 4; ++n) {
          const long col = grp + n * 16 + lr;
          v[n] = acc[m][n][r2] + (bias ? bias[col] : 0.0f);
        }
        if constexpr (AMODE == 5) {
          ushort4 a4 = *reinterpret_cast<const ushort4*>(
              &((const unsigned short*)addmat)[row * (long)N + grp + lr * 4]);
          v[0] += b2f(a4.x); v[1] += b2f(a4.y); v[2] += b2f(a4.z); v[3] += b2f(a4.w);
        }
        ushort4 o;
        o.x = f2b(v[0]); o.y = f2b(v[1]); o.z = f2b(v[2]); o.w = f2b(v[3]);
        *reinterpret_cast<ushort4*>(
            &reinterpret_cast<unsigned short*>(outp)[row * ldo + grp + lr * 4]) = o;
      }
    }
    return;
  }

  // standard epilogues
  #pragma unroll
  for (int m = 0; m < 4; ++m) {
    #pragma unroll
    for (int n = 0; n < 4; ++n) {
      const long col = grp + n * 16 + lr;
      const float bvv = bias ? bias[col] : 0.0f;
      #pragma unroll
      for (int r2 = 0; r2 < 4; ++r2) {
        const long row = bm * 128 + wm * 64 + m * 16 + lq * 4 + r2;
        float v = acc[m][n][r2] + bvv;
        if constexpr (AMODE == 3) v += ((const float*)addmat)[(long)gate_perm((int)row) * N + col];
        if constexpr (SMODE == 0) {
          reinterpret_cast<float*>(outp)[row * ldo + col] = v;
        } else if constexpr (SMODE == 1) {
          reinterpret_cast<unsigned short*>(outp)[row * ldo + col] = f2b(v);
        } else {
          const long bb = row & 1023, tt = (row >> 10) + 1;
          reinterpret_cast<float*>(outp)[bb * (T_ * MAN_) + tt * MAN_ + col] = v;
        }
      }
    }
  }
}

// ---------------- fused step kernel: h-GEMM+cell  ∥  xg slab for step t+1 ----------------
// Grid 1024 (512 step-blocks + 512 xg-blocks; last step: 512, step-only). The xg role
// (x_{t+1} @ Wx^T + TB2, K=1024, q-layout store into a 2-slab ring) is independent of
// the step's output and fills the step role's barrier-drain stalls (4 blocks/CU).
// TB is folded into xg at generation, so the step cell reads ONE ushort4 per (m,r2).
// Both roles use the m204 flat%8=XCD swizzle (XCD k owns bn in [8k,8k+8)).
__global__ __launch_bounds__(256, 2)
void step_fused(const unsigned short* __restrict__ Whh,
                const unsigned short* __restrict__ Wx,
                const unsigned short* __restrict__ Xt1,    // Xtm slab t+1 (or null)
                const unsigned short* __restrict__ xg_rd,  // ring slab t   (q-layout, TB folded)
                unsigned short* __restrict__ xg_wr,        // ring slab t+1 (or null)
                const unsigned short* __restrict__ TB2q,   // q-layout TB2 (folded into xg_wr)
                const unsigned short* __restrict__ hprev,
                unsigned short* __restrict__ hout,
                float* __restrict__ cstate)
{
  __shared__ unsigned short As[128 * 64];
  __shared__ unsigned short Bs[128 * 64];
  const int tid = threadIdx.x, lane = tid & 63, wave = tid >> 6;
  const int flat = (int)blockIdx.x;
  const bool isStep = flat < 512;
  const int f = isStep ? flat : flat - 512;
  const int j = f >> 3;
  const long bm = j >> 3;                       // 8 values
  const long bn = (long)(f & 7) * 8 + (j & 7);  // 64 values, XCD-contiguous
  const int wm = wave >> 1, wn = wave & 1;
  const int lr = lane & 15, lq = lane >> 4;

  const unsigned short* Abase = isStep ? hprev : Xt1;
  const unsigned short* Wbase = isStep ? Whh : Wx;
  const long lda = isStep ? HID_ : FEAT_;       // == W row stride for both roles
  const int nkt = isStep ? (HID_ >> 6) : (FEAT_ >> 6);

  f32x4 acc[4][4] = {};

  for (int kt = 0; kt < nkt; ++kt) {
    const int ko = kt << 6;
    __syncthreads();
    #pragma unroll
    for (int it = 0; it < 4; ++it) {
      const int c0 = it * 256 + wave * 64;
      const int c = c0 + lane;
      const int row = c >> 3, sub = c & 7;
      gload16(Abase + (bm * 128 + row) * lda + ko + sub * 8, &As[c0 * 8]);
      gload16(Wbase + (bn * 128 + row) * lda + ko + sub * 8, &Bs[c0 * 8]);
    }
    __syncthreads();
    #pragma unroll
    for (int kk = 0; kk < 2; ++kk) {
      short8 av[4], bv[4];
      const int lk = kk * 32 + lq * 8;
      #pragma unroll
      for (int m = 0; m < 4; ++m)
        av[m] = *reinterpret_cast<const short8*>(&As[(wm * 64 + m * 16 + lr) * 64 + lk]);
      #pragma unroll
      for (int n = 0; n < 4; ++n)
        bv[n] = *reinterpret_cast<const short8*>(&Bs[(wn * 64 + n * 16 + lr) * 64 + lk]);
      #pragma unroll
      for (int m = 0; m < 4; ++m)
        #pragma unroll
        for (int n = 0; n < 4; ++n)
          acc[m][n] = __builtin_amdgcn_mfma_f32_16x16x32_bf16(av[m], bv[n], acc[m][n], 0, 0, 0);
    }
  }

  const long grp = bn * 128 + wn * 64;

  if (isStep) {
    // fused LSTM cell: n=0..3 fragments are i,f,g,o for h = bn*32+wn*16+lr
    // xg_rd already includes x@Wx^T + TB -> single ushort4 read per (m,r2)
    const int hcol = (int)bn * 32 + wn * 16 + lr;
    #pragma unroll
    for (int m = 0; m < 4; ++m) {
      #pragma unroll
      for (int r2 = 0; r2 < 4; ++r2) {
        const long row = bm * 128 + wm * 64 + m * 16 + lq * 4 + r2;
        ushort4 gq = *reinterpret_cast<const ushort4*>(&xg_rd[row * (long)NG_ + grp + lr * 4]);
        float gi = acc[m][0][r2] + b2f(gq.x);
        float gf = acc[m][1][r2] + b2f(gq.y);
        float gg = acc[m][2][r2] + b2f(gq.z);
        float go = acc[m][3][r2] + b2f(gq.w);
        const long ci = row * HID_ + hcol;
        float c = cstate[ci];
        c = sigmoidf_(gf) * c + sigmoidf_(gi) * tanh_fast(gg);
        cstate[ci] = c;
        hout[ci] = f2b(sigmoidf_(go) * tanh_fast(c));
      }
    }
  } else {
    // q-layout bf16 store of x_{t+1} gates + TB2 into ring slab t+1
    #pragma unroll
    for (int m = 0; m < 4; ++m) {
      #pragma unroll
      for (int r2 = 0; r2 < 4; ++r2) {
        const long row = bm * 128 + wm * 64 + m * 16 + lq * 4 + r2;
        const long qbase = row * (long)NG_ + grp + lr * 4;
        ushort4 tq = *reinterpret_cast<const ushort4*>(&TB2q[qbase]);
        ushort4 o;
        o.x = f2b(acc[m][0][r2] + b2f(tq.x));
        o.y = f2b(acc[m][1][r2] + b2f(tq.y));
        o.z = f2b(acc[m][2][r2] + b2f(tq.z));
        o.w = f2b(acc[m][3][r2] + b2f(tq.w));
        *reinterpret_cast<ushort4*>(&xg_wr[qbase]) = o;
      }
    }
  }
}

// ---------------- launcher ----------------
extern "C" void kernel_launch(void* const* d_in, const int* in_sizes, int n_in,
                              void* d_out, int out_size, void* d_ws, size_t ws_size,
                              hipStream_t stream) {
  const float* input_repr = (const float*)d_in[0];
  const float* time_enc   = (const float*)d_in[1];
  const float* y0         = (const float*)d_in[2];
  const float* W_ih       = (const float*)d_in[3];
  const float* b_ih       = (const float*)d_in[4];
  const float* W_hh       = (const float*)d_in[5];
  const float* b_hh       = (const float*)d_in[6];
  const float* W_mu       = (const float*)d_in[7];
  const float* b_mu       = (const float*)d_in[8];
  float* out = (float*)d_out;

  char* ws = (char*)d_ws;
  auto alloc = [&](size_t bytes) {
    char* p = ws; ws += (bytes + 255) & ~(size_t)255; return p;
  };
  unsigned short* Xtm    = (unsigned short*)alloc((size_t)T_ * B_ * FEAT_ * 2);   // 134 MB (time-major)
  unsigned short* hstore = (unsigned short*)alloc((size_t)T_ * B_ * HID_ * 2);    // 268 MB
  float*  cst   = (float*)alloc((size_t)B_ * HID_ * 4);                           // 8.4 MB
  unsigned short* TB2 = (unsigned short*)alloc((size_t)B_ * NG_ * 2);             // 16.8 MB (bf16, q-layout)
  unsigned short* TB1 = (unsigned short*)alloc((size_t)B_ * NG_ * 2);             // 16.8 MB (q-layout)
  unsigned short* Whhf  = (unsigned short*)alloc((size_t)NG_ * HID_ * 2);         // 33.5 MB (perm rows)
  unsigned short* Wxbf  = (unsigned short*)alloc((size_t)NG_ * FEAT_ * 2);        // 16.8 MB (perm rows)
  unsigned short* Wybf  = (unsigned short*)alloc((size_t)NG_ * MAN_ * 2);         // (perm rows)
  unsigned short* Wtebf = (unsigned short*)alloc((size_t)NG_ * TENC_ * 2);        // (perm rows)
  unsigned short* WmuT  = (unsigned short*)alloc((size_t)HID_ * MAN_ * 2);
  unsigned short* Wmubf = (unsigned short*)alloc((size_t)MAN_ * HID_ * 2);
  unsigned short* tebf  = (unsigned short*)alloc((size_t)B_ * TENC_ * 2);
  unsigned short* y0bf  = (unsigned short*)alloc((size_t)B_ * MAN_ * 2);
  float* bvec2 = (float*)alloc(NG_ * 4);
  float* nbm   = (float*)alloc(NG_ * 4);
  size_t base_bytes = (size_t)(ws - (char*)d_ws);
  // xg 2-slab ring (33.6 MB), q-layout, TB folded in
  size_t xg_bytes = (size_t)2 * B_ * NG_ * 2;
  bool use_xg = (base_bytes + xg_bytes + 4096) <= ws_size;
  unsigned short* xgring = use_xg ? (unsigned short*)alloc(xg_bytes) : nullptr;

  // --- conversions / preps (all parallel work) ---
  pack_x_tm<<<B_ * T_, 256, 0, stream>>>(input_repr, Xtm);
  pack_wih<<<dim3(2, NG_), 256, 0, stream>>>(W_ih, Wxbf, Wybf, Wtebf);
  pack_bf16<<<dim3(2, MAN_), 256, 0, stream>>>(W_mu, HID_, 0, Wmubf, HID_);
  pack_bf16<<<dim3(1, B_), 256, 0, stream>>>(time_enc, TENC_, 0, tebf, TENC_);
  pack_bf16<<<dim3(1, B_), 256, 0, stream>>>(y0, MAN_, 0, y0bf, MAN_);
  transpose_to_bf16<<<1024, 256, 0, stream>>>(W_mu, WmuT);
  bias_prep<<<NG_ / 256, 256, 0, stream>>>(W_ih, b_ih, b_hh, b_mu, bvec2, nbm);
  zero_u32<<<(B_ * HID_ / 2 + 255) / 256, 256, 0, stream>>>((unsigned int*)hstore, (long)B_ * HID_ / 2); // h0 = 0
  zero_u32<<<(B_ * HID_ + 255) / 256, 256, 0, stream>>>((unsigned int*)cst, (long)B_ * HID_);            // c0 = 0
  out_t0<<<B_ * MAN_ / 256, 256, 0, stream>>>(y0, out);

  // Whhf = perm(W_hh) + permWy @ W_mu   (bf16, rows permuted)   M=NG_, N=HID_, K=MAN_
  gemm_bt<1, 3><<<dim3(NG_ / 128, HID_ / 128), 256, 0, stream>>>(
      Wybf, MAN_, Wybf, MAN_, MAN_, WmuT, WmuT, HID_, MAN_,
      nullptr, W_hh, nullptr, Whhf, HID_, nullptr, nullptr);
  // TB2 = q(te @ permWte^T + bvec2)                M=B_, N=NG_, K=TENC_ (bf16 q-layout)
  gemm_bt<4, 0><<<dim3(B_ / 128, NG_ / 128), 256, 0, stream>>>(
      tebf, TENC_, tebf, TENC_, TENC_, Wtebf, Wtebf, NG_, TENC_,
      bvec2, nullptr, nullptr, TB2, NG_, nullptr, nullptr);
  // TB1 = q(y0 @ permWy^T + nbm) + TB2(q)          M=B_, N=NG_, K=MAN_ (bf16 q-layout)
  gemm_bt<4, 5><<<dim3(B_ / 128, NG_ / 128), 256, 0, stream>>>(
      y0bf, MAN_, y0bf, MAN_, MAN_, Wybf, Wybf, NG_, MAN_,
      nbm, TB2, nullptr, TB1, NG_, nullptr, nullptr);

  if (use_xg) {
    // prologue: xg slab for t=1 into ring[1] = x_1 @ permWx^T + TB1  (q-layout)
    gemm_bt<4, 5><<<dim3(B_ / 128, NG_ / 128), 256, 0, stream>>>(
        Xtm + (long)B_ * FEAT_, FEAT_, Xtm, FEAT_, 1024,
        Wxbf, Wxbf, NG_, 1024,
        nullptr, TB1, nullptr, xgring + (size_t)B_ * NG_, NG_, nullptr, nullptr);

    // 63 fused steps: h-GEMM+cell (slab t) ∥ xg+TB2 GEMM (slab t+1)
    for (int t = 1; t < T_; ++t) {
      const bool hasxg = (t + 1 < T_);
      step_fused<<<hasxg ? 1024 : 512, 256, 0, stream>>>(
          Whhf, Wxbf,
          hasxg ? Xtm + (long)(t + 1) * B_ * FEAT_ : nullptr,
          xgring + (size_t)(t & 1) * B_ * NG_,
          hasxg ? xgring + (size_t)((t + 1) & 1) * B_ * NG_ : nullptr,
          TB2,
          hstore + (long)(t - 1) * B_ * HID_,
          hstore + (long)t * B_ * HID_,
          cst);
    }
  } else {
    // fallback (R2-proven path): per-step K=3072 two-region GEMM + fused cell
    for (int t = 1; t < T_; ++t) {
      const unsigned short* A1 = Xtm + (long)t * B_ * FEAT_;
      const unsigned short* A2 = hstore + (long)(t - 1) * B_ * HID_;
      gemm_bt<3, 0><<<dim3(B_ / 128, NG_ / 128), 256, 0, stream>>>(
          A1, FEAT_, A2, HID_, FEAT_,
          Wxbf, Whhf, NG_, FEAT_ + HID_,
          nullptr, nullptr, (t == 1 ? TB1 : TB2), nullptr, 0,
          cst, hstore + (long)t * B_ * HID_);
    }
  }

  // --- all outputs y_t = h_t @ W_mu^T + b_mu in one GEMM, scattered into (B,T,MAN) ---
  gemm_bt<2, 0><<<dim3((T_ - 1) * B_ / 128, MAN_ / 128), 256, 0, stream>>>(
      hstore + (long)B_ * HID_, HID_, hstore + (long)B_ * HID_, HID_, HID_,
      Wmubf, Wmubf, MAN_, HID_,
      b_mu, nullptr, nullptr, out, 0, nullptr, nullptr);
}

// Round 11
// 4368.377 us; speedup vs baseline: 2.1587x; 1.0256x over previous
//
#include <hip/hip_runtime.h>
#include <hip/hip_bf16.h>

#define B_ 1024
#define T_ 64
#define FEAT_ 1024
#define TENC_ 256
#define MAN_ 128
#define HID_ 2048
#define NG_ 8192   /* 4*HID */
#define IND_ 1408

typedef __attribute__((ext_vector_type(8))) short short8;
typedef __attribute__((ext_vector_type(4))) float f32x4;

typedef const __attribute__((address_space(1))) void as1_cvoid;
typedef __attribute__((address_space(3))) void as3_void;

static __device__ __forceinline__ float sigmoidf_(float x) {
  return 1.0f / (1.0f + __expf(-x));
}
static __device__ __forceinline__ float tanh_fast(float x) {
  return 1.0f - 2.0f / (__expf(2.0f * x) + 1.0f);
}
static __device__ __forceinline__ unsigned short f2b(float x) {
  __hip_bfloat16 h = __float2bfloat16(x);
  return *reinterpret_cast<unsigned short*>(&h);
}
static __device__ __forceinline__ float b2f(unsigned short u) {
  unsigned int v = ((unsigned int)u) << 16;
  return *reinterpret_cast<float*>(&v);
}

// gate permutation: new col p -> original gate-matrix row
// gate = (p>>4)&3, h = (p>>7)*32 + ((p>>6)&1)*16 + (p&15)
static __device__ __forceinline__ int gate_perm(int p) {
  int h = ((p >> 7) << 5) + (((p >> 6) & 1) << 4) + (p & 15);
  int gate = (p >> 4) & 3;
  return gate * HID_ + h;
}

__device__ __forceinline__ void gload16(const unsigned short* g, unsigned short* l) {
  __builtin_amdgcn_global_load_lds((as1_cvoid*)g, (as3_void*)l, 16, 0, 0);
}

// ---------------- small prep kernels ----------------

__global__ void zero_u32(unsigned int* p, long n) {
  long i = (long)blockIdx.x * blockDim.x + threadIdx.x;
  if (i < n) p[i] = 0u;
}

// X [b][t][f] fp32 -> Xtm [t][b][f] bf16
__global__ void pack_x_tm(const float* __restrict__ src, unsigned short* __restrict__ dst) {
  int c = threadIdx.x * 4;
  int bt = blockIdx.x;
  int b = bt >> 6, t = bt & 63;
  float4 v = *reinterpret_cast<const float4*>(&src[((long)b * T_ + t) * FEAT_ + c]);
  ushort4 o;
  o.x = f2b(v.x); o.y = f2b(v.y); o.z = f2b(v.z); o.w = f2b(v.w);
  *reinterpret_cast<ushort4*>(&dst[((long)t * B_ + b) * FEAT_ + c]) = o;
}

// fp32 (rows x cols slice) -> contiguous bf16
__global__ void pack_bf16(const float* __restrict__ src, long ld, long off,
                          unsigned short* __restrict__ dst, long cols) {
  long c = ((long)blockIdx.x * blockDim.x + threadIdx.x) * 4;
  if (c >= cols) return;
  long r = blockIdx.y;
  float4 v = *reinterpret_cast<const float4*>(&src[r * ld + off + c]);
  ushort4 o;
  o.x = f2b(v.x); o.y = f2b(v.y); o.z = f2b(v.z); o.w = f2b(v.w);
  *reinterpret_cast<ushort4*>(&dst[r * cols + c]) = o;
}

// one-pass W_ih split: row rd (gate-permuted from src), cols -> Wx | Wy | Wte (bf16)
__global__ void pack_wih(const float* __restrict__ W_ih,
                         unsigned short* __restrict__ Wx,
                         unsigned short* __restrict__ Wy,
                         unsigned short* __restrict__ Wte) {
  int c = (blockIdx.x * 256 + threadIdx.x) * 4;
  if (c >= IND_) return;
  long rd = blockIdx.y;
  long rs = gate_perm((int)rd);
  float4 v = *reinterpret_cast<const float4*>(&W_ih[rs * IND_ + c]);
  ushort4 o;
  o.x = f2b(v.x); o.y = f2b(v.y); o.z = f2b(v.z); o.w = f2b(v.w);
  if (c < FEAT_) {
    *reinterpret_cast<ushort4*>(&Wx[rd * FEAT_ + c]) = o;
  } else if (c < FEAT_ + MAN_) {
    *reinterpret_cast<ushort4*>(&Wy[rd * MAN_ + (c - FEAT_)]) = o;
  } else {
    *reinterpret_cast<ushort4*>(&Wte[rd * TENC_ + (c - FEAT_ - MAN_)]) = o;
  }
}

// WmuT[n][m] = bf16(W_mu[m][n]);  W_mu: (MAN_, HID_)
__global__ void transpose_to_bf16(const float* __restrict__ src, unsigned short* __restrict__ dst) {
  int i = blockIdx.x * 256 + threadIdx.x;       // over HID_*MAN_
  int n = i >> 7, m = i & 127;
  dst[i] = f2b(src[(long)m * HID_ + n]);
}

// permuted: bvec2[p] = (b_ih + b_hh + b_mu@Wy^T)[gate_perm(p)];  nbm[p] = -(b_mu@Wy^T)[gate_perm(p)]
__global__ void bias_prep(const float* __restrict__ W_ih, const float* __restrict__ b_ih,
                          const float* __restrict__ b_hh, const float* __restrict__ b_mu,
                          float* __restrict__ bvec2, float* __restrict__ nbm) {
  int p = blockIdx.x * 256 + threadIdx.x;
  if (p >= NG_) return;
  int g = gate_perm(p);
  const float* wy = &W_ih[(long)g * IND_ + FEAT_];
  float s = 0.f;
  #pragma unroll 8
  for (int m = 0; m < MAN_; ++m) s += b_mu[m] * wy[m];
  bvec2[p] = b_ih[g] + b_hh[g] + s;
  nbm[p] = -s;
}

__global__ void out_t0(const float* __restrict__ y0, float* __restrict__ out) {
  int i = blockIdx.x * 256 + threadIdx.x;       // over B_*MAN_
  int b = i >> 7, m = i & 127;
  out[(long)b * (T_ * MAN_) + m] = y0[i];
}

// ---------------- generic bf16 MFMA GEMM: C = A @ W^T (+bias[col]) (+addmat) ----------
// (prep / prologue / final GEMMs; R2-proven single-buffer 2-barrier structure)
// SMODE: 0 fp32 store; 1 bf16 store; 2 decoder scatter; 3 fused cell (q addmat/addmat2);
//        4 bf16 q-layout store. AMODE: 0 none; 3 fp32 addmat[gate_perm(row)*N+col];
//        5 bf16 q-layout addmat.
template<int SMODE, int AMODE>
__global__ __launch_bounds__(256, 2)
void gemm_bt(const unsigned short* __restrict__ A1, long lda1,
             const unsigned short* __restrict__ A2, long lda2, int K1,
             const unsigned short* __restrict__ W1, const unsigned short* __restrict__ W2,
             int N, int K,
             const float* __restrict__ bias,
             const void* __restrict__ addmat, const void* __restrict__ addmat2,
             void* __restrict__ outp, long ldo,
             float* __restrict__ cstate, unsigned short* __restrict__ hout)
{
  __shared__ unsigned short As[128 * 64];
  __shared__ unsigned short Bs[128 * 64];
  const int tid = threadIdx.x, lane = tid & 63, wave = tid >> 6;
  const long bm = blockIdx.x, bn = blockIdx.y;

  f32x4 acc[4][4] = {};

  const int nkt = K >> 6;
  const int wm = wave >> 1, wn = wave & 1;
  const int lr = lane & 15, lq = lane >> 4;

  for (int kt = 0; kt < nkt; ++kt) {
    const int k0 = kt << 6;
    const unsigned short* Ab; long lda; const unsigned short* Wb; long ldw; int ko;
    if (k0 < K1) { Ab = A1; lda = lda1; Wb = W1; ldw = K1;      ko = k0; }
    else         { Ab = A2; lda = lda2; Wb = W2; ldw = K - K1;  ko = k0 - K1; }
    __syncthreads();
    #pragma unroll
    for (int it = 0; it < 4; ++it) {
      const int c0 = it * 256 + wave * 64;
      const int c = c0 + lane;
      const int row = c >> 3, sub = c & 7;
      gload16(Ab + (bm * 128 + row) * lda + ko + sub * 8, &As[c0 * 8]);
      gload16(Wb + (bn * 128 + row) * ldw + ko + sub * 8, &Bs[c0 * 8]);
    }
    __syncthreads();
    #pragma unroll
    for (int kk = 0; kk < 2; ++kk) {
      short8 av[4], bv[4];
      const int lk = kk * 32 + lq * 8;
      #pragma unroll
      for (int m = 0; m < 4; ++m)
        av[m] = *reinterpret_cast<const short8*>(&As[(wm * 64 + m * 16 + lr) * 64 + lk]);
      #pragma unroll
      for (int n = 0; n < 4; ++n)
        bv[n] = *reinterpret_cast<const short8*>(&Bs[(wn * 64 + n * 16 + lr) * 64 + lk]);
      #pragma unroll
      for (int m = 0; m < 4; ++m)
        #pragma unroll
        for (int n = 0; n < 4; ++n)
          acc[m][n] = __builtin_amdgcn_mfma_f32_16x16x32_bf16(av[m], bv[n], acc[m][n], 0, 0, 0);
    }
  }

  const long grp = bn * 128 + wn * 64;

  if constexpr (SMODE == 3) {
    const int hcol = (int)bn * 32 + wn * 16 + lr;
    #pragma unroll
    for (int m = 0; m < 4; ++m) {
      #pragma unroll
      for (int r2 = 0; r2 < 4; ++r2) {
        const long row = bm * 128 + wm * 64 + m * 16 + lq * 4 + r2;
        const long qbase = row * (long)N + grp + lr * 4;
        ushort4 tq = *reinterpret_cast<const ushort4*>(
            &((const unsigned short*)addmat2)[qbase]);
        float gi = acc[m][0][r2] + b2f(tq.x);
        float gf = acc[m][1][r2] + b2f(tq.y);
        float gg = acc[m][2][r2] + b2f(tq.z);
        float go = acc[m][3][r2] + b2f(tq.w);
        if (addmat) {
          ushort4 gq = *reinterpret_cast<const ushort4*>(
              &((const unsigned short*)addmat)[qbase]);
          gi += b2f(gq.x); gf += b2f(gq.y); gg += b2f(gq.z); go += b2f(gq.w);
        }
        const long ci = row * HID_ + hcol;
        float c = cstate[ci];
        c = sigmoidf_(gf) * c + sigmoidf_(gi) * tanh_fast(gg);
        cstate[ci] = c;
        hout[ci] = f2b(sigmoidf_(go) * tanh_fast(c));
      }
    }
    return;
  }

  if constexpr (SMODE == 4) {
    #pragma unroll
    for (int m = 0; m < 4; ++m) {
      #pragma unroll
      for (int r2 = 0; r2 < 4; ++r2) {
        const long row = bm * 128 + wm * 64 + m * 16 + lq * 4 + r2;
        float v[4];
        #pragma unroll
        for (int n = 0; n < 4; ++n) {
          const long col = grp + n * 16 + lr;
          v[n] = acc[m][n][r2] + (bias ? bias[col] : 0.0f);
        }
        if constexpr (AMODE == 5) {
          ushort4 a4 = *reinterpret_cast<const ushort4*>(
              &((const unsigned short*)addmat)[row * (long)N + grp + lr * 4]);
          v[0] += b2f(a4.x); v[1] += b2f(a4.y); v[2] += b2f(a4.z); v[3] += b2f(a4.w);
        }
        ushort4 o;
        o.x = f2b(v[0]); o.y = f2b(v[1]); o.z = f2b(v[2]); o.w = f2b(v[3]);
        *reinterpret_cast<ushort4*>(
            &reinterpret_cast<unsigned short*>(outp)[row * ldo + grp + lr * 4]) = o;
      }
    }
    return;
  }

  // standard epilogues
  #pragma unroll
  for (int m = 0; m < 4; ++m) {
    #pragma unroll
    for (int n = 0; n < 4; ++n) {
      const long col = grp + n * 16 + lr;
      const float bvv = bias ? bias[col] : 0.0f;
      #pragma unroll
      for (int r2 = 0; r2 < 4; ++r2) {
        const long row = bm * 128 + wm * 64 + m * 16 + lq * 4 + r2;
        float v = acc[m][n][r2] + bvv;
        if constexpr (AMODE == 3) v += ((const float*)addmat)[(long)gate_perm((int)row) * N + col];
        if constexpr (SMODE == 0) {
          reinterpret_cast<float*>(outp)[row * ldo + col] = v;
        } else if constexpr (SMODE == 1) {
          reinterpret_cast<unsigned short*>(outp)[row * ldo + col] = f2b(v);
        } else {
          const long bb = row & 1023, tt = (row >> 10) + 1;
          reinterpret_cast<float*>(outp)[bb * (T_ * MAN_) + tt * MAN_ + col] = v;
        }
      }
    }
  }
}

// ---------------- fused step kernel: h-GEMM+cell  ∥  xg slab for step t+1 ----------------
// Grid 1024 (512 step-blocks + 512 xg-blocks; last step: 512, step-only). The xg role
// (x_{t+1} @ Wx^T, K=1024, q-layout store into a 2-slab ring) is independent of the
// step's output and fills the step role's barrier-drain stalls (4 blocks/CU co-resident).
// Both roles use the m204 flat%8=XCD swizzle (XCD k owns bn in [8k,8k+8)).
__global__ __launch_bounds__(256, 2)
void step_fused(const unsigned short* __restrict__ Whh,
                const unsigned short* __restrict__ Wx,
                const unsigned short* __restrict__ Xt1,    // Xtm slab t+1 (or null)
                const unsigned short* __restrict__ xg_rd,  // ring slab t   (q-layout)
                unsigned short* __restrict__ xg_wr,        // ring slab t+1 (or null)
                const unsigned short* __restrict__ TBq,    // q-layout TB for step t
                const unsigned short* __restrict__ hprev,
                unsigned short* __restrict__ hout,
                float* __restrict__ cstate)
{
  __shared__ unsigned short As[128 * 64];
  __shared__ unsigned short Bs[128 * 64];
  const int tid = threadIdx.x, lane = tid & 63, wave = tid >> 6;
  const int flat = (int)blockIdx.x;
  const bool isStep = flat < 512;
  const int f = isStep ? flat : flat - 512;
  const int j = f >> 3;
  const long bm = j >> 3;                       // 8 values
  const long bn = (long)(f & 7) * 8 + (j & 7);  // 64 values, XCD-contiguous
  const int wm = wave >> 1, wn = wave & 1;
  const int lr = lane & 15, lq = lane >> 4;

  const unsigned short* Abase = isStep ? hprev : Xt1;
  const unsigned short* Wbase = isStep ? Whh : Wx;
  const long lda = isStep ? HID_ : FEAT_;       // == W row stride for both roles
  const int nkt = isStep ? (HID_ >> 6) : (FEAT_ >> 6);

  f32x4 acc[4][4] = {};

  for (int kt = 0; kt < nkt; ++kt) {
    const int ko = kt << 6;
    __syncthreads();
    #pragma unroll
    for (int it = 0; it < 4; ++it) {
      const int c0 = it * 256 + wave * 64;
      const int c = c0 + lane;
      const int row = c >> 3, sub = c & 7;
      gload16(Abase + (bm * 128 + row) * lda + ko + sub * 8, &As[c0 * 8]);
      gload16(Wbase + (bn * 128 + row) * lda + ko + sub * 8, &Bs[c0 * 8]);
    }
    __syncthreads();
    #pragma unroll
    for (int kk = 0; kk < 2; ++kk) {
      short8 av[4], bv[4];
      const int lk = kk * 32 + lq * 8;
      #pragma unroll
      for (int m = 0; m < 4; ++m)
        av[m] = *reinterpret_cast<const short8*>(&As[(wm * 64 + m * 16 + lr) * 64 + lk]);
      #pragma unroll
      for (int n = 0; n < 4; ++n)
        bv[n] = *reinterpret_cast<const short8*>(&Bs[(wn * 64 + n * 16 + lr) * 64 + lk]);
      #pragma unroll
      for (int m = 0; m < 4; ++m)
        #pragma unroll
        for (int n = 0; n < 4; ++n)
          acc[m][n] = __builtin_amdgcn_mfma_f32_16x16x32_bf16(av[m], bv[n], acc[m][n], 0, 0, 0);
    }
  }

  const long grp = bn * 128 + wn * 64;

  if (isStep) {
    // fused LSTM cell: n=0..3 fragments are i,f,g,o for h = bn*32+wn*16+lr
    const int hcol = (int)bn * 32 + wn * 16 + lr;
    #pragma unroll
    for (int m = 0; m < 4; ++m) {
      #pragma unroll
      for (int r2 = 0; r2 < 4; ++r2) {
        const long row = bm * 128 + wm * 64 + m * 16 + lq * 4 + r2;
        const long qbase = row * (long)NG_ + grp + lr * 4;
        ushort4 gq = *reinterpret_cast<const ushort4*>(&xg_rd[qbase]);
        ushort4 tq = *reinterpret_cast<const ushort4*>(&TBq[qbase]);
        float gi = acc[m][0][r2] + b2f(gq.x) + b2f(tq.x);
        float gf = acc[m][1][r2] + b2f(gq.y) + b2f(tq.y);
        float gg = acc[m][2][r2] + b2f(gq.z) + b2f(tq.z);
        float go = acc[m][3][r2] + b2f(gq.w) + b2f(tq.w);
        const long ci = row * HID_ + hcol;
        float c = cstate[ci];
        c = sigmoidf_(gf) * c + sigmoidf_(gi) * tanh_fast(gg);
        cstate[ci] = c;
        hout[ci] = f2b(sigmoidf_(go) * tanh_fast(c));
      }
    }
  } else {
    // q-layout bf16 store of x_{t+1} gates into ring slab t+1
    #pragma unroll
    for (int m = 0; m < 4; ++m) {
      #pragma unroll
      for (int r2 = 0; r2 < 4; ++r2) {
        const long row = bm * 128 + wm * 64 + m * 16 + lq * 4 + r2;
        ushort4 o;
        o.x = f2b(acc[m][0][r2]); o.y = f2b(acc[m][1][r2]);
        o.z = f2b(acc[m][2][r2]); o.w = f2b(acc[m][3][r2]);
        *reinterpret_cast<ushort4*>(&xg_wr[row * (long)NG_ + grp + lr * 4]) = o;
      }
    }
  }
}

// ---------------- launcher ----------------
extern "C" void kernel_launch(void* const* d_in, const int* in_sizes, int n_in,
                              void* d_out, int out_size, void* d_ws, size_t ws_size,
                              hipStream_t stream) {
  const float* input_repr = (const float*)d_in[0];
  const float* time_enc   = (const float*)d_in[1];
  const float* y0         = (const float*)d_in[2];
  const float* W_ih       = (const float*)d_in[3];
  const float* b_ih       = (const float*)d_in[4];
  const float* W_hh       = (const float*)d_in[5];
  const float* b_hh       = (const float*)d_in[6];
  const float* W_mu       = (const float*)d_in[7];
  const float* b_mu       = (const float*)d_in[8];
  float* out = (float*)d_out;

  char* ws = (char*)d_ws;
  auto alloc = [&](size_t bytes) {
    char* p = ws; ws += (bytes + 255) & ~(size_t)255; return p;
  };
  unsigned short* Xtm    = (unsigned short*)alloc((size_t)T_ * B_ * FEAT_ * 2);   // 134 MB (time-major)
  unsigned short* hstore = (unsigned short*)alloc((size_t)T_ * B_ * HID_ * 2);    // 268 MB
  float*  cst   = (float*)alloc((size_t)B_ * HID_ * 4);                           // 8.4 MB
  unsigned short* TB2 = (unsigned short*)alloc((size_t)B_ * NG_ * 2);             // 16.8 MB (bf16, q-layout)
  unsigned short* TB1 = (unsigned short*)alloc((size_t)B_ * NG_ * 2);             // 16.8 MB (q-layout)
  unsigned short* Whhf  = (unsigned short*)alloc((size_t)NG_ * HID_ * 2);         // 33.5 MB (perm rows)
  unsigned short* Wxbf  = (unsigned short*)alloc((size_t)NG_ * FEAT_ * 2);        // 16.8 MB (perm rows)
  unsigned short* Wybf  = (unsigned short*)alloc((size_t)NG_ * MAN_ * 2);         // (perm rows)
  unsigned short* Wtebf = (unsigned short*)alloc((size_t)NG_ * TENC_ * 2);        // (perm rows)
  unsigned short* WmuT  = (unsigned short*)alloc((size_t)HID_ * MAN_ * 2);
  unsigned short* Wmubf = (unsigned short*)alloc((size_t)MAN_ * HID_ * 2);
  unsigned short* tebf  = (unsigned short*)alloc((size_t)B_ * TENC_ * 2);
  unsigned short* y0bf  = (unsigned short*)alloc((size_t)B_ * MAN_ * 2);
  float* bvec2 = (float*)alloc(NG_ * 4);
  float* nbm   = (float*)alloc(NG_ * 4);
  size_t base_bytes = (size_t)(ws - (char*)d_ws);
  // xg 2-slab ring (33.6 MB), q-layout
  size_t xg_bytes = (size_t)2 * B_ * NG_ * 2;
  bool use_xg = (base_bytes + xg_bytes + 4096) <= ws_size;
  unsigned short* xgring = use_xg ? (unsigned short*)alloc(xg_bytes) : nullptr;

  // --- conversions / preps (all parallel work) ---
  pack_x_tm<<<B_ * T_, 256, 0, stream>>>(input_repr, Xtm);
  pack_wih<<<dim3(2, NG_), 256, 0, stream>>>(W_ih, Wxbf, Wybf, Wtebf);
  pack_bf16<<<dim3(2, MAN_), 256, 0, stream>>>(W_mu, HID_, 0, Wmubf, HID_);
  pack_bf16<<<dim3(1, B_), 256, 0, stream>>>(time_enc, TENC_, 0, tebf, TENC_);
  pack_bf16<<<dim3(1, B_), 256, 0, stream>>>(y0, MAN_, 0, y0bf, MAN_);
  transpose_to_bf16<<<1024, 256, 0, stream>>>(W_mu, WmuT);
  bias_prep<<<NG_ / 256, 256, 0, stream>>>(W_ih, b_ih, b_hh, b_mu, bvec2, nbm);
  zero_u32<<<(B_ * HID_ / 2 + 255) / 256, 256, 0, stream>>>((unsigned int*)hstore, (long)B_ * HID_ / 2); // h0 = 0
  zero_u32<<<(B_ * HID_ + 255) / 256, 256, 0, stream>>>((unsigned int*)cst, (long)B_ * HID_);            // c0 = 0
  out_t0<<<B_ * MAN_ / 256, 256, 0, stream>>>(y0, out);

  // Whhf = perm(W_hh) + permWy @ W_mu   (bf16, rows permuted)   M=NG_, N=HID_, K=MAN_
  gemm_bt<1, 3><<<dim3(NG_ / 128, HID_ / 128), 256, 0, stream>>>(
      Wybf, MAN_, Wybf, MAN_, MAN_, WmuT, WmuT, HID_, MAN_,
      nullptr, W_hh, nullptr, Whhf, HID_, nullptr, nullptr);
  // TB2 = q(te @ permWte^T + bvec2)                M=B_, N=NG_, K=TENC_ (bf16 q-layout)
  gemm_bt<4, 0><<<dim3(B_ / 128, NG_ / 128), 256, 0, stream>>>(
      tebf, TENC_, tebf, TENC_, TENC_, Wtebf, Wtebf, NG_, TENC_,
      bvec2, nullptr, nullptr, TB2, NG_, nullptr, nullptr);
  // TB1 = q(y0 @ permWy^T + nbm) + TB2(q)          M=B_, N=NG_, K=MAN_ (bf16 q-layout)
  gemm_bt<4, 5><<<dim3(B_ / 128, NG_ / 128), 256, 0, stream>>>(
      y0bf, MAN_, y0bf, MAN_, MAN_, Wybf, Wybf, NG_, MAN_,
      nbm, TB2, nullptr, TB1, NG_, nullptr, nullptr);

  if (use_xg) {
    // prologue: xg slab for t=1 into ring[1]   (M=B_, K=1024, q-layout)
    gemm_bt<4, 0><<<dim3(B_ / 128, NG_ / 128), 256, 0, stream>>>(
        Xtm + (long)B_ * FEAT_, FEAT_, Xtm, FEAT_, 1024,
        Wxbf, Wxbf, NG_, 1024,
        nullptr, nullptr, nullptr, xgring + (size_t)B_ * NG_, NG_, nullptr, nullptr);

    // 63 fused steps: h-GEMM+cell (slab t) ∥ xg GEMM (slab t+1)
    for (int t = 1; t < T_; ++t) {
      const bool hasxg = (t + 1 < T_);
      step_fused<<<hasxg ? 1024 : 512, 256, 0, stream>>>(
          Whhf, Wxbf,
          hasxg ? Xtm + (long)(t + 1) * B_ * FEAT_ : nullptr,
          xgring + (size_t)(t & 1) * B_ * NG_,
          hasxg ? xgring + (size_t)((t + 1) & 1) * B_ * NG_ : nullptr,
          (t == 1 ? TB1 : TB2),
          hstore + (long)(t - 1) * B_ * HID_,
          hstore + (long)t * B_ * HID_,
          cst);
    }
  } else {
    // fallback: per-step K=3072 two-region GEMM + fused cell (TB via q-addmat2)
    for (int t = 1; t < T_; ++t) {
      const unsigned short* A1 = Xtm + (long)t * B_ * FEAT_;
      const unsigned short* A2 = hstore + (long)(t - 1) * B_ * HID_;
      gemm_bt<3, 0><<<dim3(B_ / 128, NG_ / 128), 256, 0, stream>>>(
          A1, FEAT_, A2, HID_, FEAT_,
          Wxbf, Whhf, NG_, FEAT_ + HID_,
          nullptr, nullptr, (t == 1 ? TB1 : TB2), nullptr, 0,
          cst, hstore + (long)t * B_ * HID_);
    }
  }

  // --- all outputs y_t = h_t @ W_mu^T + b_mu in one GEMM, scattered into (B,T,MAN) ---
  gemm_bt<2, 0><<<dim3((T_ - 1) * B_ / 128, MAN_ / 128), 256, 0, stream>>>(
      hstore + (long)B_ * HID_, HID_, hstore + (long)B_ * HID_, HID_, HID_,
      Wmubf, Wmubf, MAN_, HID_,
      b_mu, nullptr, nullptr, out, 0, nullptr, nullptr);
}